// Round 1
// baseline (399.743 us; speedup 1.0000x reference)
//
#include <hip/hip_runtime.h>
#include <stdint.h>

typedef unsigned long long ull;

#define NBOX 20000
#define NCLS 80
#define KC 256
#define LCAP 1024
#define IOU_THR 0.5f
#define SCORE_THR 0.5f

// Kernel 1: one block per (batch, class). Exact stable top-256 + greedy NMS,
// writes up to 8 kept entries (key = score_bits<<32 | ~(c*256+rank), box) to ws.
__global__ __launch_bounds__(256) void nms_class_kernel(
    const float* __restrict__ boxes,   // (8,20000,4)
    const float* __restrict__ scores,  // (8,20000,80)
    ull*   __restrict__ wkeys,         // (8*80, 8)
    float* __restrict__ wboxes)        // (8*80, 8, 4)
{
  const int tid = threadIdx.x;
  const int bc  = blockIdx.x;
  const int b   = bc / NCLS;
  const int c   = bc % NCLS;
  const float* sc = scores + (size_t)b * NBOX * NCLS + c;
  const float* bx = boxes  + (size_t)b * NBOX * 4;

  __shared__ unsigned int hist[256];
  __shared__ ull L[LCAP];
  __shared__ unsigned int sSel, sKrem, sCount, sMin;
  __shared__ float kb[5];

  const int lane = tid & 63;

  // ---- R0: histogram of byte0, ballot-dedup (all [0.5,1) hit one bin) ----
  hist[tid] = 0;
  __syncthreads();
  for (int i = tid; i < NBOX; i += 256) {
    unsigned int bits = __float_as_uint(sc[(size_t)i * NCLS]);
    unsigned int bin = bits >> 24;
    ull m = __ballot(1);  // active-lane mask (guards bin==0 vs inactive lanes)
#pragma unroll
    for (int k = 0; k < 8; ++k) {
      ull v = __ballot((bin >> k) & 1);
      m &= ((bin >> k) & 1) ? v : ~v;
    }
    if (lane == __builtin_ctzll(m))
      atomicAdd(&hist[bin], (unsigned int)__builtin_popcountll(m));
  }
  __syncthreads();
  if (tid == 0) {
    unsigned int cum = 0, K = KC; int sel = 0;
    for (int h = 255; h >= 0; --h) {
      if (cum + hist[h] >= K) { sel = h; break; }
      cum += hist[h];
    }
    sSel = (unsigned int)sel;
    sKrem = K - cum;
  }
  __syncthreads();
  const unsigned int p0 = sSel;

  // ---- R1: histogram of byte1 where byte0 == p0 ----
  hist[tid] = 0;
  __syncthreads();
  for (int i = tid; i < NBOX; i += 256) {
    unsigned int bits = __float_as_uint(sc[(size_t)i * NCLS]);
    if ((bits >> 24) == p0) atomicAdd(&hist[(bits >> 16) & 0xFFu], 1u);
  }
  __syncthreads();
  if (tid == 0) {
    unsigned int cum = 0, K = sKrem; int sel = 0;
    for (int h = 255; h >= 0; --h) {
      if (cum + hist[h] >= K) { sel = h; break; }
      cum += hist[h];
    }
    sSel = (p0 << 8) | (unsigned int)sel;  // 16-bit prefix of the 256th value
    sCount = 0;
  }
  __syncthreads();
  const unsigned int p16 = sSel;

  // ---- R2: collect every element with (bits>>16) >= p16 (superset of top-256) ----
  for (int i = tid; i < NBOX; i += 256) {
    unsigned int bits = __float_as_uint(sc[(size_t)i * NCLS]);
    if ((bits >> 16) >= p16) {
      unsigned int pos = atomicAdd(&sCount, 1u);
      if (pos < LCAP) L[pos] = ((ull)bits << 32) | (unsigned int)(~(unsigned int)i);
    }
  }
  __syncthreads();
  unsigned int n = sCount < LCAP ? sCount : LCAP;
  for (int i = tid; i < LCAP; i += 256)
    if ((unsigned int)i >= n) L[i] = 0ull;
  __syncthreads();

  // ---- bitonic sort LCAP descending (key desc = score desc, idx asc on ties) ----
  for (unsigned int k = 2; k <= LCAP; k <<= 1) {
    for (unsigned int j = k >> 1; j > 0; j >>= 1) {
      for (int t = tid; t < LCAP; t += 256) {
        unsigned int ixj = (unsigned int)t ^ j;
        if (ixj > (unsigned int)t) {
          ull a = L[t], bb = L[ixj];
          bool desc = ((t & k) == 0);
          if (desc ? (a < bb) : (a > bb)) { L[t] = bb; L[ixj] = a; }
        }
      }
      __syncthreads();
    }
  }

  // ---- per-thread candidate (rank = tid) ----
  ull key = L[tid];
  unsigned int bits = (unsigned int)(key >> 32);
  float score = __uint_as_float(bits);
  unsigned int idx = ~(unsigned int)key;
  if (key == 0ull) idx = 0;  // padding safety (n>=256 guaranteed in practice)
  float4 mb = ((const float4*)bx)[idx];  // y1,x1,y2,x2
  float area = fmaxf(mb.z - mb.x, 0.f) * fmaxf(mb.w - mb.y, 0.f);
  bool alive = (key != 0ull) && (score > SCORE_THR);

  ull*   wk = wkeys  + (size_t)bc * 8;
  float* wb = wboxes + (size_t)bc * 32;

  int kept = 0;
  for (int it = 0; it < 8; ++it) {
    if (tid == 0) sMin = 0xFFFFFFFFu;
    __syncthreads();
    if (alive) atomicMin(&sMin, (unsigned int)tid);
    __syncthreads();
    unsigned int w = sMin;
    if (w == 0xFFFFFFFFu) break;  // uniform
    if ((unsigned int)tid == w) {
      kb[0] = mb.x; kb[1] = mb.y; kb[2] = mb.z; kb[3] = mb.w; kb[4] = area;
      wk[it] = ((ull)bits << 32) | (unsigned int)(~(unsigned int)(c * KC + tid));
      float* d = wb + it * 4;
      d[0] = mb.x; d[1] = mb.y; d[2] = mb.z; d[3] = mb.w;
      alive = false;  // explicit: zero-area kept box has IoU 0 with itself
    }
    __syncthreads();
    float iy1 = fmaxf(mb.x, kb[0]);
    float ix1 = fmaxf(mb.y, kb[1]);
    float iy2 = fminf(mb.z, kb[2]);
    float ix2 = fminf(mb.w, kb[3]);
    float inter = fmaxf(iy2 - iy1, 0.f) * fmaxf(ix2 - ix1, 0.f);
    float uni = area + kb[4] - inter;
    float iou = (uni > 0.f) ? (inter / uni) : 0.f;
    if (iou > IOU_THR) alive = false;
    kept = it + 1;
    __syncthreads();
  }
  // fill unused slots (ws is poisoned each launch)
  for (int j = kept + tid; j < 8; j += 256) {
    wk[j] = 0ull;
    float* d = wb + j * 4;
    d[0] = 0.f; d[1] = 0.f; d[2] = 0.f; d[3] = 0.f;
  }
}

// Kernel 2: one block per batch — global top-8 over 640 entries, write outputs.
__global__ __launch_bounds__(256) void final_topk_kernel(
    const ull*   __restrict__ wkeys,
    const float* __restrict__ wboxes,
    float* __restrict__ out)
{
  const int b = blockIdx.x;
  const int tid = threadIdx.x;
  const ull*   wk = wkeys  + (size_t)b * (NCLS * 8);
  const float* wb = wboxes + (size_t)b * (NCLS * 32);
  __shared__ ull red[256];

  ull k0 = wk[tid];
  ull k1 = wk[tid + 256];
  ull k2 = (tid < NCLS * 8 - 512) ? wk[tid + 512] : 0ull;
  int vcount = 0;

  for (int s = 0; s < 8; ++s) {
    ull lm = (k0 > k1) ? k0 : k1;
    if (k2 > lm) lm = k2;
    red[tid] = lm;
    __syncthreads();
    for (int off = 128; off > 0; off >>= 1) {
      if (tid < off && red[tid + off] > red[tid]) red[tid] = red[tid + off];
      __syncthreads();
    }
    ull best = red[0];
    __syncthreads();
    if (best != 0ull) {
      vcount++;
      int e = -1;
      if (k0 == best)      { e = tid;       k0 = 0ull; }
      else if (k1 == best) { e = tid + 256; k1 = 0ull; }
      else if (k2 == best) { e = tid + 512; k2 = 0ull; }
      if (e >= 0) {  // keys are unique -> exactly one owner
        unsigned int bits = (unsigned int)(best >> 32);
        float sv = __uint_as_float(bits);
        unsigned int flat = ~(unsigned int)best;  // c*256 + rank
        const float* bp = wb + (size_t)e * 4;
        int o = (b * 8 + s) * 4;
        out[o + 0] = fminf(fmaxf(bp[0], 0.f), 1.f);
        out[o + 1] = fminf(fmaxf(bp[1], 0.f), 1.f);
        out[o + 2] = fminf(fmaxf(bp[2], 0.f), 1.f);
        out[o + 3] = fminf(fmaxf(bp[3], 0.f), 1.f);
        out[256 + b * 8 + s] = sv;
        out[320 + b * 8 + s] = (float)(flat >> 8);  // class index
      }
    } else if (tid == 0) {
      int o = (b * 8 + s) * 4;
      out[o + 0] = 0.f; out[o + 1] = 0.f; out[o + 2] = 0.f; out[o + 3] = 0.f;
      out[256 + b * 8 + s] = 0.f;
      out[320 + b * 8 + s] = 0.f;
    }
  }
  if (tid == 0) out[384 + b] = (float)vcount;
}

extern "C" void kernel_launch(void* const* d_in, const int* in_sizes, int n_in,
                              void* d_out, int out_size, void* d_ws, size_t ws_size,
                              hipStream_t stream) {
  const float* boxes  = (const float*)d_in[0];  // (8,20000,1,4) f32
  const float* scores = (const float*)d_in[1];  // (8,20000,80)  f32
  float* out = (float*)d_out;                   // 392 floats

  // workspace: 640*8 keys (40960 B) + 640*8*4 floats (81920 B) = 122880 B
  ull*   wkeys  = (ull*)d_ws;
  float* wboxes = (float*)((char*)d_ws + (size_t)640 * 8 * sizeof(ull));

  nms_class_kernel<<<dim3(8 * NCLS), dim3(256), 0, stream>>>(boxes, scores, wkeys, wboxes);
  final_topk_kernel<<<dim3(8), dim3(256), 0, stream>>>(wkeys, wboxes, out);
}